// Round 2
// baseline (9074.150 us; speedup 1.0000x reference)
//
#include <hip/hip_runtime.h>
#include <stdint.h>
#include <stddef.h>

// ---------------- problem constants ----------------
#define SEQ 512
#define BATCH 256
#define IW 64
#define STREAM 1024
#define OW 128

// ---------------- decomposition ----------------
#define NGROUP 8     // row groups (one per XCD slot via blockIdx%8)
#define NSLICE 32    // WGs per group, each owns 32 output cols
#define CW 32        // cols per WG slice
#define RPG 32       // batch rows per group
#define NT 256       // threads per block (4 waves)

typedef __attribute__((ext_vector_type(4)))  float  f32x4;
typedef __attribute__((ext_vector_type(16))) float  f32x16;
typedef __attribute__((ext_vector_type(8)))  __bf16 bf16x8;
typedef __attribute__((ext_vector_type(8)))  short  short8;
typedef __attribute__((ext_vector_type(4)))  short  short4_t;

__device__ __forceinline__ unsigned short f2bf(float x) {
  union { float f; uint32_t u; } v; v.f = x;
  return (unsigned short)((v.u + 0x7FFFu + ((v.u >> 16) & 1u)) >> 16);
}

// ---------------- workspace layout (bytes) ----------------
#define WS_FLAGS   0                         // sflag[8] @ +0, hflag[8] @ +1024 (128B strided)
#define WS_SUMS    4096                      // [512][1024] f32  (2 MB)  zeroed
#define WS_SUMS2   (4096 + 2097152)          // [512][1024] f32  (2 MB)  zeroed
#define WS_REGT    (4096 + 4194304)          // [512] f32
#define WS_SBUF    (4096 + 4194304 + 4096)   // 8 groups x 32x1024 bf16 (512 KB)
#define WS_HBUF    (WS_SBUF + NGROUP*RPG*STREAM*2)
#define ZERO_BYTES (4096 + 4194304)

__global__ __launch_bounds__(NT, 1) void rnn_main(
    const float* __restrict__ input, const float* __restrict__ init_state,
    const float* __restrict__ aff_w, const float* __restrict__ aff_b,
    const float* __restrict__ fc1_w, const float* __restrict__ fc1_b,
    const float* __restrict__ fc2_w, const float* __restrict__ fc2_b,
    float* __restrict__ d_out, char* __restrict__ ws)
{
  // LDS: persistent bf16 weight slices (XOR-swizzled), partial/reduce scratch, biases.
  // 64K + 64K + 16K + 256B = 147.7 KB (fits 160 KB/CU -> 1 block/CU).
  __shared__ __align__(16) short W1s[NSLICE * STREAM];   // 64 KB
  __shared__ __align__(16) short W2s[NSLICE * STREAM];   // 64 KB
  __shared__ __align__(16) float partial[4 * RPG * CW];  // 16 KB (also reg colbuf)
  __shared__ __align__(16) float b1s[CW], b2s[CW];

  const int tid = threadIdx.x;
  const int g = blockIdx.x & 7;    // row group (XCD-local under round-robin dispatch; perf only)
  const int j = blockIdx.x >> 3;   // column slice 0..31

  uint32_t* sflag = (uint32_t*)(ws + WS_FLAGS) + g * 32;          // own 128B line
  uint32_t* hflag = (uint32_t*)(ws + WS_FLAGS + 1024) + g * 32;
  float* sumS  = (float*)(ws + WS_SUMS);
  float* sumS2 = (float*)(ws + WS_SUMS2);
  short* sbuf = (short*)(ws + WS_SBUF) + (size_t)g * (RPG * STREAM);
  short* hbuf = (short*)(ws + WS_HBUF) + (size_t)g * (RPG * STREAM);

  // ---- stage weight slices into LDS (fp32 -> bf16, 16B-chunk XOR swizzle) ----
  for (int idx = tid; idx < NSLICE * (STREAM / 8); idx += NT) {  // 4096 chunks
    int n = idx >> 7;          // 0..31 (slice-local output col)
    int kc = idx & 127;        // 16B chunk along K
    const float* p1 = fc1_w + (size_t)(j * CW + n) * STREAM + (kc << 3);
    const float* p2 = fc2_w + (size_t)(j * CW + n) * STREAM + (kc << 3);
    f32x4 a0 = *(const f32x4*)p1, a1 = *(const f32x4*)(p1 + 4);
    f32x4 c0 = *(const f32x4*)p2, c1 = *(const f32x4*)(p2 + 4);
    short8 w1v, w2v;
#pragma unroll
    for (int i = 0; i < 4; ++i) {
      w1v[i] = (short)f2bf(a0[i]); w1v[4 + i] = (short)f2bf(a1[i]);
      w2v[i] = (short)f2bf(c0[i]); w2v[4 + i] = (short)f2bf(c1[i]);
    }
    int boff = (n << 11) + ((kc << 4) ^ ((n & 7) << 4));
    *(short8*)((char*)W1s + boff) = w1v;
    *(short8*)((char*)W2s + boff) = w2v;
  }
  if (tid < CW) {
    b1s[tid] = fc1_b[j * CW + tid];
    b2s[tid] = fc2_b[j * CW + tid];
  }

  // ---- init s0 = aff(concat(input[0], init_state[:,64:])) ----
  const int rr_ = tid >> 3;            // row 0..31 in group
  const int c4  = (tid & 7) << 2;      // slice-local col (step 4)
  const int gc  = j * CW + c4;         // global col
  f32x4 master = {0.f, 0.f, 0.f, 0.f}; // fp32 state slice (j>=2)
  {
    f32x4 v;
    if (j >= 2) v = *(const f32x4*)(init_state + (size_t)(g * RPG + rr_) * STREAM + gc);
    else        v = *(const f32x4*)(input + (size_t)(g * RPG + rr_) * IW + gc);
    f32x4 w  = *(const f32x4*)(aff_w + gc);
    f32x4 bb = *(const f32x4*)(aff_b + gc);
    v = w * v + bb;
    if (j >= 2) master = v;
    short4_t sv;
#pragma unroll
    for (int i = 0; i < 4; ++i) sv[i] = (short)f2bf(v[i]);
    *(short4_t*)(sbuf + rr_ * STREAM + gc) = sv;
  }
  __syncthreads();
  if (tid == 0) {
    __builtin_amdgcn_fence(__ATOMIC_RELEASE, "agent");
    __hip_atomic_fetch_add(sflag, 1u, __ATOMIC_RELAXED, __HIP_MEMORY_SCOPE_AGENT);
  }

  const int ln  = tid & 63;
  const int wv  = tid >> 6;          // wave id -> K range
  const int ar  = ln & 31;           // A row / B col
  const int kof = (ln >> 5) << 3;    // lane k offset
  const int klo = wv << 8;           // 256-wide K split per wave
  const int swzB = (ar & 7) << 4;
  const char* W1c = (const char*)W1s + (ar << 11);
  const char* W2c = (const char*)W2s + (ar << 11);

  for (int t = 0; t < SEQ; ++t) {
    // ---- reg partials on s_t (own cols, fp32 exact) ----
    if (j >= 2) {
      *(f32x4*)(partial + (rr_ << 5) + c4) = master;
      __syncthreads();
      if (tid < CW) {
        float s1 = 0.f, s2 = 0.f;
#pragma unroll 4
        for (int r = 0; r < RPG; ++r) { float v = partial[(r << 5) + tid]; s1 += v; s2 += v * v; }
        atomicAdd(sumS  + t * STREAM + j * CW + tid, s1);
        atomicAdd(sumS2 + t * STREAM + j * CW + tid, s2);
      }
      __syncthreads();
    } else {
      if (tid < CW) {
        const float* ip = input + ((size_t)t * BATCH + g * RPG) * IW + j * CW + tid;
        float s1 = 0.f, s2 = 0.f;
        if (t == 0) {
          float w = aff_w[j * CW + tid], bb = aff_b[j * CW + tid];
          for (int r = 0; r < RPG; ++r) { float v = w * ip[(size_t)r * IW] + bb; s1 += v; s2 += v * v; }
        } else {
          for (int r = 0; r < RPG; ++r) { float v = ip[(size_t)r * IW]; s1 += v; s2 += v * v; }
        }
        atomicAdd(sumS  + t * STREAM + j * CW + tid, s1);
        atomicAdd(sumS2 + t * STREAM + j * CW + tid, s2);
      }
    }

    // ---- wait: s_t fully published by group ----
    if (tid == 0) {
      uint32_t tgt = (uint32_t)(32 * (t + 1));
      while (__hip_atomic_load(sflag, __ATOMIC_RELAXED, __HIP_MEMORY_SCOPE_AGENT) < tgt)
        __builtin_amdgcn_s_sleep(1);
      __builtin_amdgcn_fence(__ATOMIC_ACQUIRE, "agent");
    }
    __syncthreads();

    // ---- GEMM1: h_slice = |s @ W1slice^T + b1| (K-split over 4 waves) ----
    {
      f32x16 acc0 = {}; f32x16 acc1 = {};
      const char* sb = (const char*)sbuf;
#pragma unroll
      for (int it = 0; it < 16; it += 2) {
        int k0 = klo + (it << 4) + kof;
        int k1 = k0 + 16;
        bf16x8 a0v = *(const bf16x8*)(sb + ((size_t)((ar << 10) + k0) << 1));
        bf16x8 b0v = *(const bf16x8*)(W1c + ((k0 << 1) ^ swzB));
        acc0 = __builtin_amdgcn_mfma_f32_32x32x16_bf16(a0v, b0v, acc0, 0, 0, 0);
        bf16x8 a1v = *(const bf16x8*)(sb + ((size_t)((ar << 10) + k1) << 1));
        bf16x8 b1v = *(const bf16x8*)(W1c + ((k1 << 1) ^ swzB));
        acc1 = __builtin_amdgcn_mfma_f32_32x32x16_bf16(a1v, b1v, acc1, 0, 0, 0);
      }
      acc0 += acc1;
      float* pw = partial + (wv << 10);
#pragma unroll
      for (int i = 0; i < 16; ++i) {
        int r = (i & 3) + ((i >> 2) << 3) + ((ln >> 5) << 2);
        pw[(r << 5) + (ln & 31)] = acc0[i];
      }
    }
    __syncthreads();
    {
      f32x4 sum = *(const f32x4*)(partial + (rr_ << 5) + c4);
      sum += *(const f32x4*)(partial + 1024 + (rr_ << 5) + c4);
      sum += *(const f32x4*)(partial + 2048 + (rr_ << 5) + c4);
      sum += *(const f32x4*)(partial + 3072 + (rr_ << 5) + c4);
      f32x4 vb = *(const f32x4*)(b1s + c4);
      short4_t hv;
#pragma unroll
      for (int i = 0; i < 4; ++i) hv[i] = (short)f2bf(fabsf(sum[i] + vb[i]));
      *(short4_t*)(hbuf + rr_ * STREAM + gc) = hv;
    }
    __syncthreads();
    if (tid == 0) {
      __builtin_amdgcn_fence(__ATOMIC_RELEASE, "agent");
      __hip_atomic_fetch_add(hflag, 1u, __ATOMIC_RELAXED, __HIP_MEMORY_SCOPE_AGENT);
    }

    // ---- j<2: prefetch next input BEFORE the wait (read-only, always valid) ----
    f32x4 nxt = {0.f, 0.f, 0.f, 0.f};
    if (j < 2 && t < SEQ - 1)
      nxt = *(const f32x4*)(input + ((size_t)(t + 1) * BATCH + g * RPG + rr_) * IW + gc);

    // ---- wait: h fully published (also: all GEMM1 readers done with sbuf) ----
    if (tid == 0) {
      uint32_t tgt = (uint32_t)(32 * (t + 1));
      while (__hip_atomic_load(hflag, __ATOMIC_RELAXED, __HIP_MEMORY_SCOPE_AGENT) < tgt)
        __builtin_amdgcn_s_sleep(1);
      __builtin_amdgcn_fence(__ATOMIC_ACQUIRE, "agent");
    }
    __syncthreads();

    // ---- GEMM2 (state cols) or next-input staging (cols 0..63 are dead in out) ----
    if (j >= 2) {
      f32x16 acc0 = {}; f32x16 acc1 = {};
      const char* hb = (const char*)hbuf;
#pragma unroll
      for (int it = 0; it < 16; it += 2) {
        int k0 = klo + (it << 4) + kof;
        int k1 = k0 + 16;
        bf16x8 a0v = *(const bf16x8*)(hb + ((size_t)((ar << 10) + k0) << 1));
        bf16x8 b0v = *(const bf16x8*)(W2c + ((k0 << 1) ^ swzB));
        acc0 = __builtin_amdgcn_mfma_f32_32x32x16_bf16(a0v, b0v, acc0, 0, 0, 0);
        bf16x8 a1v = *(const bf16x8*)(hb + ((size_t)((ar << 10) + k1) << 1));
        bf16x8 b1v = *(const bf16x8*)(W2c + ((k1 << 1) ^ swzB));
        acc1 = __builtin_amdgcn_mfma_f32_32x32x16_bf16(a1v, b1v, acc1, 0, 0, 0);
      }
      acc0 += acc1;
      float* pw = partial + (wv << 10);
#pragma unroll
      for (int i = 0; i < 16; ++i) {
        int r = (i & 3) + ((i >> 2) << 3) + ((ln >> 5) << 2);
        pw[(r << 5) + (ln & 31)] = acc0[i];
      }
      __syncthreads();
      f32x4 sum = *(const f32x4*)(partial + (rr_ << 5) + c4);
      sum += *(const f32x4*)(partial + 1024 + (rr_ << 5) + c4);
      sum += *(const f32x4*)(partial + 2048 + (rr_ << 5) + c4);
      sum += *(const f32x4*)(partial + 3072 + (rr_ << 5) + c4);
      f32x4 vb = *(const f32x4*)(b2s + c4);
#pragma unroll
      for (int i = 0; i < 4; ++i)
        master[i] = 0.97f * master[i] + 0.03f * (sum[i] + vb[i]);
      short4_t sv;
#pragma unroll
      for (int i = 0; i < 4; ++i) sv[i] = (short)f2bf(master[i]);
      *(short4_t*)(sbuf + rr_ * STREAM + gc) = sv;
    } else {
      if (t < SEQ - 1) {
        short4_t sv;
#pragma unroll
        for (int i = 0; i < 4; ++i) sv[i] = (short)f2bf(nxt[i]);
        *(short4_t*)(sbuf + rr_ * STREAM + gc) = sv;
      }
    }
    __syncthreads();
    if (tid == 0) {
      __builtin_amdgcn_fence(__ATOMIC_RELEASE, "agent");
      __hip_atomic_fetch_add(sflag, 1u, __ATOMIC_RELAXED, __HIP_MEMORY_SCOPE_AGENT);
    }
  }

  // ---- final output: last 128 cols (fp32 master) ----
  if (j >= 28) {
    float* dst = d_out + (size_t)(g * RPG + rr_) * OW + (j - 28) * CW + c4;
    *(f32x4*)dst = master;
  }
}

__global__ void reg_reduce1(const float* __restrict__ sumS, const float* __restrict__ sumS2,
                            float* __restrict__ regt) {
  int t = blockIdx.x;
  float acc = 0.f;
  for (int c = threadIdx.x; c < STREAM; c += 256) {
    float s1 = sumS[t * STREAM + c];
    float s2 = sumS2[t * STREAM + c];
    float m = s1 * (1.0f / 256.0f);
    float var = (s2 - 256.0f * m * m) * (1.0f / 255.0f);
    float d1 = fabsf(m);
    acc += (d1 < 1.f) ? 0.5f * d1 * d1 : d1 - 0.5f;
    float d2 = fabsf(var - 1.f);
    acc += (d2 < 1.f) ? 0.5f * d2 * d2 : d2 - 0.5f;
  }
#pragma unroll
  for (int off = 32; off > 0; off >>= 1) acc += __shfl_down(acc, off, 64);
  __shared__ float red[4];
  if ((threadIdx.x & 63) == 0) red[threadIdx.x >> 6] = acc;
  __syncthreads();
  if (threadIdx.x == 0)
    regt[t] = (red[0] + red[1] + red[2] + red[3]) * (1.0f / 1024.0f);
}

__global__ void reg_reduce2(const float* __restrict__ regt, float* __restrict__ out_reg) {
  float acc = regt[threadIdx.x] + regt[threadIdx.x + 256];
#pragma unroll
  for (int off = 32; off > 0; off >>= 1) acc += __shfl_down(acc, off, 64);
  __shared__ float red[4];
  if ((threadIdx.x & 63) == 0) red[threadIdx.x >> 6] = acc;
  __syncthreads();
  if (threadIdx.x == 0)
    out_reg[0] = (red[0] + red[1] + red[2] + red[3]) * (1.0f / 512.0f);
}

extern "C" void kernel_launch(void* const* d_in, const int* in_sizes, int n_in,
                              void* d_out, int out_size, void* d_ws, size_t ws_size,
                              hipStream_t stream) {
  (void)in_sizes; (void)n_in; (void)out_size; (void)ws_size;
  const float* input      = (const float*)d_in[0];
  const float* init_state = (const float*)d_in[1];
  const float* aff_w      = (const float*)d_in[2];
  const float* aff_b      = (const float*)d_in[3];
  const float* fc1_w      = (const float*)d_in[4];
  const float* fc1_b      = (const float*)d_in[5];
  const float* fc2_w      = (const float*)d_in[6];
  const float* fc2_b      = (const float*)d_in[7];
  float* out = (float*)d_out;
  char* ws = (char*)d_ws;

  // flags + reg accumulators must be zero (ws is poisoned 0xAA before each call)
  hipMemsetAsync(ws, 0, ZERO_BYTES, stream);

  void* args[] = { &input, &init_state, &aff_w, &aff_b, &fc1_w, &fc1_b, &fc2_w, &fc2_b, &out, &ws };
  hipError_t err = hipLaunchCooperativeKernel((void*)rnn_main, dim3(NGROUP * NSLICE), dim3(NT),
                                              args, 0, stream);
  if (err != hipSuccess) {
    // 256 blocks @ ~148 KB LDS force 1 block/CU on 256 CUs -> co-resident anyway.
    hipLaunchKernelGGL(rnn_main, dim3(NGROUP * NSLICE), dim3(NT), 0, stream,
                       input, init_state, aff_w, aff_b, fc1_w, fc1_b, fc2_w, fc2_b, out, ws);
  }

  float* sumS  = (float*)(ws + WS_SUMS);
  float* sumS2 = (float*)(ws + WS_SUMS2);
  float* regt  = (float*)(ws + WS_REGT);
  hipLaunchKernelGGL(reg_reduce1, dim3(SEQ), dim3(256), 0, stream, sumS, sumS2, regt);
  hipLaunchKernelGGL(reg_reduce2, dim3(1), dim3(256), 0, stream, regt, out + 32768);
}

// Round 7
// 2874.971 us; speedup vs baseline: 3.1563x; 3.1563x over previous
//
#include <hip/hip_runtime.h>
#include <stdint.h>
#include <stddef.h>

// ---------------- problem constants ----------------
#define SEQ 512
#define BATCH 256
#define IW 64
#define STREAM 1024
#define OW 128

// ---------------- decomposition ----------------
#define NGROUP 8     // row groups
#define NSLICE 32    // WGs per group, each owns 32 output cols
#define CW 32        // cols per WG slice
#define RPG 32       // batch rows per group
#define NT 256       // threads per block (4 waves)

typedef __attribute__((ext_vector_type(4)))  float  f32x4;
typedef __attribute__((ext_vector_type(16))) float  f32x16;
typedef __attribute__((ext_vector_type(8)))  __bf16 bf16x8;
typedef __attribute__((ext_vector_type(8)))  short  short8;

__device__ __forceinline__ unsigned short f2bf(float x) {
  union { float f; uint32_t u; } v; v.f = x;
  return (unsigned short)((v.u + 0x7FFFu + ((v.u >> 16) & 1u)) >> 16);
}
__device__ __forceinline__ uint64_t pack4bf(f32x4 v) {
  return (uint64_t)f2bf(v[0]) | ((uint64_t)f2bf(v[1]) << 16)
       | ((uint64_t)f2bf(v[2]) << 32) | ((uint64_t)f2bf(v[3]) << 48);
}
// MALL-coherent (bypass L1/L2) load/store — the exchange transport.
__device__ __forceinline__ f32x4 ld_mall(const void* p) {
  f32x4 r;
  asm volatile("global_load_dwordx4 %0, %1, off sc0 sc1" : "=v"(r) : "v"(p) : "memory");
  return r;
}
__device__ __forceinline__ void st_mall(void* p, uint64_t v) {
  asm volatile("global_store_dwordx2 %0, %1, off sc0 sc1" :: "v"(p), "v"(v) : "memory");
}
// rule #18: sched_barrier(0) after inline-asm waitcnt so MFMAs can't hoist above it.
#define WAIT_VM(N) do { asm volatile("s_waitcnt vmcnt(" #N ")" ::: "memory"); \
                        __builtin_amdgcn_sched_barrier(0); } while (0)

// Exchange layout: fragment-order blocks. addr(row, k) for the 4-col group at k:
// chunk c = k>>3 (16B of one row), block = c>>1 (1 KB), halves interleaved.
__device__ __forceinline__ int xoff(int rr, int k) {
  int c = k >> 3;
  return ((c >> 1) << 10) + ((c & 1) << 9) + (rr << 4) + ((k & 4) << 1);
}

// ---------------- workspace layout (bytes) ----------------
#define WS_FLAGS   0                         // sflag[8] @ +0, hflag[8] @ +1024 (128B strided)
#define WS_SUMS    4096                      // [512][1024] f32  (2 MB)  zeroed
#define WS_SUMS2   (4096 + 2097152)          // [512][1024] f32  (2 MB)  zeroed
#define WS_REGT    (4096 + 4194304)          // [512] f32
#define WS_SBUF    (4096 + 4194304 + 4096)   // 8 groups x 64 KB bf16 (fragment-order)
#define WS_HBUF    (WS_SBUF + NGROUP*RPG*STREAM*2)
#define ZERO_BYTES (4096 + 4194304)

__global__ __launch_bounds__(NT, 1) void rnn_main(
    const float* __restrict__ input, const float* __restrict__ init_state,
    const float* __restrict__ aff_w, const float* __restrict__ aff_b,
    const float* __restrict__ fc1_w, const float* __restrict__ fc1_b,
    const float* __restrict__ fc2_w, const float* __restrict__ fc2_b,
    float* __restrict__ d_out, char* __restrict__ ws)
{
  // LDS: persistent bf16 weight slices (XOR-swizzled) + reduce scratch + biases.
  __shared__ __align__(16) short W1s[NSLICE * STREAM];   // 64 KB
  __shared__ __align__(16) short W2s[NSLICE * STREAM];   // 64 KB
  __shared__ __align__(16) float partial[4 * RPG * CW];  // 16 KB
  __shared__ __align__(16) float b1s[CW], b2s[CW];

  const int tid = threadIdx.x;
  const int g = blockIdx.x & 7;    // row group
  const int j = blockIdx.x >> 3;   // column slice 0..31

  uint32_t* sflag = (uint32_t*)(ws + WS_FLAGS) + g * 32;          // own 128B line
  uint32_t* hflag = (uint32_t*)(ws + WS_FLAGS + 1024) + g * 32;
  float* sumS  = (float*)(ws + WS_SUMS);
  float* sumS2 = (float*)(ws + WS_SUMS2);
  char* sbuf_c = ws + WS_SBUF + (size_t)g * (RPG * STREAM * 2);
  char* hbuf_c = ws + WS_HBUF + (size_t)g * (RPG * STREAM * 2);

  // ---- stage weight slices into LDS (fp32 -> bf16, 16B-chunk XOR swizzle) ----
  for (int idx = tid; idx < NSLICE * (STREAM / 8); idx += NT) {  // 4096 chunks
    int n = idx >> 7;          // slice-local output col 0..31
    int kc = idx & 127;        // 16B chunk along K
    const float* p1 = fc1_w + (size_t)(j * CW + n) * STREAM + (kc << 3);
    const float* p2 = fc2_w + (size_t)(j * CW + n) * STREAM + (kc << 3);
    f32x4 a0 = *(const f32x4*)p1, a1 = *(const f32x4*)(p1 + 4);
    f32x4 c0 = *(const f32x4*)p2, c1 = *(const f32x4*)(p2 + 4);
    short8 w1v, w2v;
#pragma unroll
    for (int i = 0; i < 4; ++i) {
      w1v[i] = (short)f2bf(a0[i]); w1v[4 + i] = (short)f2bf(a1[i]);
      w2v[i] = (short)f2bf(c0[i]); w2v[4 + i] = (short)f2bf(c1[i]);
    }
    int boff = (n << 11) + ((kc << 4) ^ ((n & 7) << 4));
    *(short8*)((char*)W1s + boff) = w1v;
    *(short8*)((char*)W2s + boff) = w2v;
  }
  if (tid < CW) {
    b1s[tid] = fc1_b[j * CW + tid];
    b2s[tid] = fc2_b[j * CW + tid];
  }

  const int rr_ = tid >> 3;            // row 0..31 in group
  const int c4  = (tid & 7) << 2;      // slice-local col (step 4)
  const int gc  = j * CW + c4;         // global col
  f32x4 master = {0.f, 0.f, 0.f, 0.f};

  // ---- init s0 = aff(concat(input[0], init_state[:,64:])), publish + stats(0) ----
  {
    f32x4 v;
    if (j >= 2) v = *(const f32x4*)(init_state + (size_t)(g * RPG + rr_) * STREAM + gc);
    else        v = *(const f32x4*)(input + (size_t)(g * RPG + rr_) * IW + gc);
    f32x4 w  = *(const f32x4*)(aff_w + gc);
    f32x4 bb = *(const f32x4*)(aff_b + gc);
    v = w * v + bb;
    if (j >= 2) master = v;
    st_mall(sbuf_c + xoff(rr_, gc), pack4bf(v));
    *(f32x4*)(partial + (rr_ << 5) + c4) = v;        // stats staging (fp32 exact)
  }
  WAIT_VM(0);
  __syncthreads();   // weights staged + sbuf stores drained + partial visible
  if (tid == 0)
    __hip_atomic_fetch_add(sflag, 1u, __ATOMIC_RELAXED, __HIP_MEMORY_SCOPE_AGENT);
  if (tid < CW) {    // stats for s_0 (off critical path)
    float s1 = 0.f, s2 = 0.f;
#pragma unroll 4
    for (int r = 0; r < RPG; ++r) { float v = partial[(r << 5) + tid]; s1 += v; s2 += v * v; }
    atomicAdd(sumS  + j * CW + tid, s1);
    atomicAdd(sumS2 + j * CW + tid, s2);
  }

  const int ln  = tid & 63;
  const int wv  = tid >> 6;          // wave id -> K quarter
  const int ar  = ln & 31;           // B col (W output col)
  const int kof = (ln >> 5) << 3;    // lane k offset for B fragment
  const int klo = wv << 8;           // 256-wide K split per wave
  const int swzB = (ar & 7) << 4;
  const char* W1c = (const char*)W1s + (ar << 11);
  const char* W2c = (const char*)W2s + (ar << 11);
  const char* pa_s = sbuf_c + (wv << 14) + (ln << 4);  // A-fragment base (s)
  const char* pa_h = hbuf_c + (wv << 14) + (ln << 4);  // A-fragment base (h)

  for (int t = 0; t < SEQ; ++t) {
    // ---- wait: s_t fully published by group ----
    if (tid == 0) {
      uint32_t tgt = 32u * (t + 1);
      while (__hip_atomic_load(sflag, __ATOMIC_RELAXED, __HIP_MEMORY_SCOPE_AGENT) < tgt)
        __builtin_amdgcn_s_sleep(1);
    }
    __syncthreads();

    // ---- GEMM1: h_slice = |s @ W1slice^T + b1| (A direct from MALL) ----
    {
      f32x4 a[16];
#pragma unroll
      for (int it = 0; it < 16; ++it) a[it] = ld_mall(pa_s + (it << 10));
      bf16x8 bf[16];
#pragma unroll
      for (int it = 0; it < 16; ++it)
        bf[it] = *(const bf16x8*)(W1c + (((klo + (it << 4) + kof) << 1) ^ swzB));
      f32x16 acc0 = {}, acc1 = {};
      WAIT_VM(8);
#pragma unroll
      for (int it = 0; it < 8; it += 2) {
        acc0 = __builtin_amdgcn_mfma_f32_32x32x16_bf16(__builtin_bit_cast(bf16x8, a[it]),     bf[it],     acc0, 0, 0, 0);
        acc1 = __builtin_amdgcn_mfma_f32_32x32x16_bf16(__builtin_bit_cast(bf16x8, a[it + 1]), bf[it + 1], acc1, 0, 0, 0);
      }
      WAIT_VM(0);
#pragma unroll
      for (int it = 8; it < 16; it += 2) {
        acc0 = __builtin_amdgcn_mfma_f32_32x32x16_bf16(__builtin_bit_cast(bf16x8, a[it]),     bf[it],     acc0, 0, 0, 0);
        acc1 = __builtin_amdgcn_mfma_f32_32x32x16_bf16(__builtin_bit_cast(bf16x8, a[it + 1]), bf[it + 1], acc1, 0, 0, 0);
      }
      acc0 += acc1;
      float* pw = partial + (wv << 10);
#pragma unroll
      for (int i = 0; i < 16; ++i) {
        int r = (i & 3) + ((i >> 2) << 3) + ((ln >> 5) << 2);
        pw[(r << 5) + (ln & 31)] = acc0[i];
      }
    }
    __syncthreads();
    {
      f32x4 sum = *(const f32x4*)(partial + (rr_ << 5) + c4);
      sum += *(const f32x4*)(partial + 1024 + (rr_ << 5) + c4);
      sum += *(const f32x4*)(partial + 2048 + (rr_ << 5) + c4);
      sum += *(const f32x4*)(partial + 3072 + (rr_ << 5) + c4);
      f32x4 vb = *(const f32x4*)(b1s + c4);
      f32x4 hv;
#pragma unroll
      for (int i = 0; i < 4; ++i) hv[i] = fabsf(sum[i] + vb[i]);
      st_mall(hbuf_c + xoff(rr_, gc), pack4bf(hv));
    }
    WAIT_VM(0);
    __syncthreads();
    if (tid == 0)
      __hip_atomic_fetch_add(hflag, 1u, __ATOMIC_RELAXED, __HIP_MEMORY_SCOPE_AGENT);

    // ---- wait: h fully published (also: all GEMM1 readers done with sbuf) ----
    if (tid == 0) {
      uint32_t tgt = 32u * (t + 1);
      while (__hip_atomic_load(hflag, __ATOMIC_RELAXED, __HIP_MEMORY_SCOPE_AGENT) < tgt)
        __builtin_amdgcn_s_sleep(1);
    }
    __syncthreads();

    // ---- GEMM2 (state cols) or next-input staging (cols 0..63 dead in out) ----
    f32x4 nxt = {0.f, 0.f, 0.f, 0.f};
    if (j >= 2) {
      f32x4 a[16];
#pragma unroll
      for (int it = 0; it < 16; ++it) a[it] = ld_mall(pa_h + (it << 10));
      bf16x8 bf[16];
#pragma unroll
      for (int it = 0; it < 16; ++it)
        bf[it] = *(const bf16x8*)(W2c + (((klo + (it << 4) + kof) << 1) ^ swzB));
      f32x16 acc0 = {}, acc1 = {};
      WAIT_VM(8);
#pragma unroll
      for (int it = 0; it < 8; it += 2) {
        acc0 = __builtin_amdgcn_mfma_f32_32x32x16_bf16(__builtin_bit_cast(bf16x8, a[it]),     bf[it],     acc0, 0, 0, 0);
        acc1 = __builtin_amdgcn_mfma_f32_32x32x16_bf16(__builtin_bit_cast(bf16x8, a[it + 1]), bf[it + 1], acc1, 0, 0, 0);
      }
      WAIT_VM(0);
#pragma unroll
      for (int it = 8; it < 16; it += 2) {
        acc0 = __builtin_amdgcn_mfma_f32_32x32x16_bf16(__builtin_bit_cast(bf16x8, a[it]),     bf[it],     acc0, 0, 0, 0);
        acc1 = __builtin_amdgcn_mfma_f32_32x32x16_bf16(__builtin_bit_cast(bf16x8, a[it + 1]), bf[it + 1], acc1, 0, 0, 0);
      }
      acc0 += acc1;
      float* pw = partial + (wv << 10);
#pragma unroll
      for (int i = 0; i < 16; ++i) {
        int r = (i & 3) + ((i >> 2) << 3) + ((ln >> 5) << 2);
        pw[(r << 5) + (ln & 31)] = acc0[i];
      }
      __syncthreads();
      f32x4 sum = *(const f32x4*)(partial + (rr_ << 5) + c4);
      sum += *(const f32x4*)(partial + 1024 + (rr_ << 5) + c4);
      sum += *(const f32x4*)(partial + 2048 + (rr_ << 5) + c4);
      sum += *(const f32x4*)(partial + 3072 + (rr_ << 5) + c4);
      f32x4 vb = *(const f32x4*)(b2s + c4);
#pragma unroll
      for (int i = 0; i < 4; ++i)
        master[i] = 0.97f * master[i] + 0.03f * (sum[i] + vb[i]);
      if (t < SEQ - 1)
        st_mall(sbuf_c + xoff(rr_, gc), pack4bf(master));
    } else {
      // j<2: idle during GEMM2 -> load & stage next input here (latency is free)
      if (t < SEQ - 1) {
        nxt = *(const f32x4*)(input + ((size_t)(t + 1) * BATCH + g * RPG + rr_) * IW + gc);
        st_mall(sbuf_c + xoff(rr_, gc), pack4bf(nxt));
      }
    }

    // ---- publish s_{t+1} + stats(t+1), stats reduce off critical path ----
    __syncthreads();                              // GEMM2 slab reads done
    if (t < SEQ - 1)
      *(f32x4*)(partial + (rr_ << 5) + c4) = (j >= 2) ? master : nxt;
    WAIT_VM(0);
    __syncthreads();
    if (tid == 0)
      __hip_atomic_fetch_add(sflag, 1u, __ATOMIC_RELAXED, __HIP_MEMORY_SCOPE_AGENT);
    if (t < SEQ - 1 && tid < CW) {
      float s1 = 0.f, s2 = 0.f;
#pragma unroll 4
      for (int r = 0; r < RPG; ++r) { float v = partial[(r << 5) + tid]; s1 += v; s2 += v * v; }
      atomicAdd(sumS  + (size_t)(t + 1) * STREAM + j * CW + tid, s1);
      atomicAdd(sumS2 + (size_t)(t + 1) * STREAM + j * CW + tid, s2);
    }
  }

  // ---- final output: last 128 cols (fp32 master) ----
  if (j >= 28) {
    float* dst = d_out + (size_t)(g * RPG + rr_) * OW + (j - 28) * CW + c4;
    *(f32x4*)dst = master;
  }
}

__global__ void reg_reduce1(const float* __restrict__ sumS, const float* __restrict__ sumS2,
                            float* __restrict__ regt) {
  int t = blockIdx.x;
  float acc = 0.f;
  for (int c = threadIdx.x; c < STREAM; c += 256) {
    float s1 = sumS[t * STREAM + c];
    float s2 = sumS2[t * STREAM + c];
    float m = s1 * (1.0f / 256.0f);
    float var = (s2 - 256.0f * m * m) * (1.0f / 255.0f);
    float d1 = fabsf(m);
    acc += (d1 < 1.f) ? 0.5f * d1 * d1 : d1 - 0.5f;
    float d2 = fabsf(var - 1.f);
    acc += (d2 < 1.f) ? 0.5f * d2 * d2 : d2 - 0.5f;
  }
#pragma unroll
  for (int off = 32; off > 0; off >>= 1) acc += __shfl_down(acc, off, 64);
  __shared__ float red[4];
  if ((threadIdx.x & 63) == 0) red[threadIdx.x >> 6] = acc;
  __syncthreads();
  if (threadIdx.x == 0)
    regt[t] = (red[0] + red[1] + red[2] + red[3]) * (1.0f / 1024.0f);
}

__global__ void reg_reduce2(const float* __restrict__ regt, float* __restrict__ out_reg) {
  float acc = regt[threadIdx.x] + regt[threadIdx.x + 256];
#pragma unroll
  for (int off = 32; off > 0; off >>= 1) acc += __shfl_down(acc, off, 64);
  __shared__ float red[4];
  if ((threadIdx.x & 63) == 0) red[threadIdx.x >> 6] = acc;
  __syncthreads();
  if (threadIdx.x == 0)
    out_reg[0] = (red[0] + red[1] + red[2] + red[3]) * (1.0f / 512.0f);
}

extern "C" void kernel_launch(void* const* d_in, const int* in_sizes, int n_in,
                              void* d_out, int out_size, void* d_ws, size_t ws_size,
                              hipStream_t stream) {
  (void)in_sizes; (void)n_in; (void)out_size; (void)ws_size;
  const float* input      = (const float*)d_in[0];
  const float* init_state = (const float*)d_in[1];
  const float* aff_w      = (const float*)d_in[2];
  const float* aff_b      = (const float*)d_in[3];
  const float* fc1_w      = (const float*)d_in[4];
  const float* fc1_b      = (const float*)d_in[5];
  const float* fc2_w      = (const float*)d_in[6];
  const float* fc2_b      = (const float*)d_in[7];
  float* out = (float*)d_out;
  char* ws = (char*)d_ws;

  // flags + reg accumulators must be zero (ws is poisoned 0xAA before each call)
  hipMemsetAsync(ws, 0, ZERO_BYTES, stream);

  void* args[] = { &input, &init_state, &aff_w, &aff_b, &fc1_w, &fc1_b, &fc2_w, &fc2_b, &out, &ws };
  hipError_t err = hipLaunchCooperativeKernel((void*)rnn_main, dim3(NGROUP * NSLICE), dim3(NT),
                                              args, 0, stream);
  if (err != hipSuccess) {
    // 256 blocks @ ~148 KB LDS force 1 block/CU on 256 CUs -> co-resident anyway.
    hipLaunchKernelGGL(rnn_main, dim3(NGROUP * NSLICE), dim3(NT), 0, stream,
                       input, init_state, aff_w, aff_b, fc1_w, fc1_b, fc2_w, fc2_b, out, ws);
  }

  float* sumS  = (float*)(ws + WS_SUMS);
  float* sumS2 = (float*)(ws + WS_SUMS2);
  float* regt  = (float*)(ws + WS_REGT);
  hipLaunchKernelGGL(reg_reduce1, dim3(SEQ), dim3(256), 0, stream, sumS, sumS2, regt);
  hipLaunchKernelGGL(reg_reduce2, dim3(1), dim3(256), 0, stream, regt, out + 32768);
}